// Round 4
// baseline (352.850 us; speedup 1.0000x reference)
//
#include <hip/hip_runtime.h>
#include <hip/hip_cooperative_groups.h>

namespace cg = cooperative_groups;

#define B 8
#define N 4096
#define NITER 4
#define NBLK 256          // one block per CU -> cooperative co-residency guaranteed
#define TPB 1024          // 16 waves/block, 4 waves/SIMD
#define CPB (N / NBLK)    // 16 columns of the output owned per block

// Fused diffusion: P held in registers across ALL iterations (loaded once).
// Decomposition: block owns 16 output columns x all 4096 b.
//   wave w (16/block): b-range [w*256, w*256+256)
//   lane l: column c = c0 + (l&15), q = l>>4 -> b-sub-range [w*256 + q*64, +64)
//   => each lane holds p[64] = P[b][c] slice in VGPRs (64 regs).
// Per iteration: lane product over its 64 b (pred read as predT[b][0..7], two
// dwordx4, L2-hot, shared by 16 lanes) -> shfl product over q -> LDS product
// over 16 waves -> block writes its 16x8 outputs -> grid.sync.
// Iterate state is transposed predT ping-pong (buf0/buf1, 128 KB each in ws);
// only the final iteration writes row-major d_out.
__global__ __launch_bounds__(TPB, 4) void fused_kernel(
        const float* __restrict__ P,
        const float* __restrict__ predsT,   // [N][B] transposed initial preds
        const float* __restrict__ maskT,    // [N][B] transposed seed mask
        float* __restrict__ buf0,           // [N][B] ping
        float* __restrict__ buf1,           // [N][B] pong
        float* __restrict__ out)            // [B][N] final output
{
    cg::grid_group grid = cg::this_grid();

    const int tid   = threadIdx.x;
    const int wave  = tid >> 6;          // 0..15
    const int lane  = tid & 63;
    const int cc    = lane & 15;         // col within block
    const int q     = lane >> 4;         // 0..3
    const int c0    = blockIdx.x * CPB;
    const int c     = c0 + cc;
    const int bbase = wave * 256 + q * 64;

    // ---- one-time P load into registers: p[j] = P[bbase+j][c]
    // Fully unrolled: 64 independent loads in flight -> HBM-saturating phase.
    float p[64];
#pragma unroll
    for (int j = 0; j < 64; ++j)
        p[j] = P[(size_t)(bbase + j) * N + c];

    __shared__ float redbuf[16][16][B];   // [wave][col][batch] = 8 KB

    for (int it = 0; it < NITER; ++it) {
        // ping-pong: it0: predsT->buf0, it1: buf0->buf1, it2: buf1->buf0, it3: buf0->out
        const float* src = (it == 0) ? predsT : ((it == 2) ? buf1 : buf0);

        float prod[B];
#pragma unroll
        for (int i = 0; i < B; ++i) prod[i] = 1.0f;

        const float* sp = src + (size_t)bbase * B;
#pragma unroll
        for (int j = 0; j < 64; ++j) {
            const float4 lo = *reinterpret_cast<const float4*>(sp + j * B);
            const float4 hi = *reinterpret_cast<const float4*>(sp + j * B + 4);
            const float pj = p[j];
            prod[0] *= fmaf(-pj, lo.x, 1.0f);
            prod[1] *= fmaf(-pj, lo.y, 1.0f);
            prod[2] *= fmaf(-pj, lo.z, 1.0f);
            prod[3] *= fmaf(-pj, lo.w, 1.0f);
            prod[4] *= fmaf(-pj, hi.x, 1.0f);
            prod[5] *= fmaf(-pj, hi.y, 1.0f);
            prod[6] *= fmaf(-pj, hi.z, 1.0f);
            prod[7] *= fmaf(-pj, hi.w, 1.0f);
        }

        // product across the 4 q-groups (lanes l, l^16, l^32, l^48 share a column)
#pragma unroll
        for (int i = 0; i < B; ++i) {
            prod[i] *= __shfl_xor(prod[i], 16);
            prod[i] *= __shfl_xor(prod[i], 32);
        }
        if (lane < 16) {
#pragma unroll
            for (int i = 0; i < B; ++i) redbuf[wave][cc][i] = prod[i];
        }
        __syncthreads();

        // wave 0: product across 16 waves; 128 (col,batch) pairs, 2 per lane
        if (wave == 0) {
#pragma unroll
            for (int rep = 0; rep < 2; ++rep) {
                const int pidx = lane + rep * 64;
                const int rc = pidx >> 3;    // col 0..15
                const int ri = pidx & 7;     // batch 0..7
                float r = 1.0f;
#pragma unroll
                for (int w = 0; w < 16; ++w) r *= redbuf[w][rc][ri];
                float v = 1.0f - r;
                if (maskT[(size_t)(c0 + rc) * B + ri] != 0.0f) v = 1.0f;
                if (it < NITER - 1) {
                    float* dst = (it == 1) ? buf1 : buf0;
                    dst[(size_t)(c0 + rc) * B + ri] = v;
                } else {
                    out[(size_t)ri * N + (c0 + rc)] = v;   // final row-major
                }
            }
        }
        if (it < NITER - 1) grid.sync();   // also provides the block-level barrier
                                           // protecting redbuf reuse next iter
    }
}

// Transpose preds into predT layout + scatter seed mask (maskT pre-zeroed by memset).
__global__ void prep_kernel(const float* __restrict__ preds,
                            const int* __restrict__ seed_idx, int nseeds,
                            float* __restrict__ predsT, float* __restrict__ maskT) {
    const int t = blockIdx.x * blockDim.x + threadIdx.x;   // t = i*N + n
    if (t < B * N) {
        const int i = t / N;
        const int n = t % N;
        predsT[(size_t)n * B + i] = preds[t];              // read coalesced, write scattered (tiny)
    }
    if (t < nseeds) {
        const int b = seed_idx[2 * t + 0];
        const int n = seed_idx[2 * t + 1];
        maskT[(size_t)n * B + b] = 1.0f;
    }
}

extern "C" void kernel_launch(void* const* d_in, const int* in_sizes, int n_in,
                              void* d_out, int out_size, void* d_ws, size_t ws_size,
                              hipStream_t stream) {
    const float* preds    = (const float*)d_in[0];   // [B, N]
    const float* P        = (const float*)d_in[1];   // [N, N]
    const int*   seed_idx = (const int*)d_in[2];     // [NSEEDS, 2]
    const int nseeds = in_sizes[2] / 2;

    float* out = (float*)d_out;                      // [B, N]
    float* buf0   = (float*)d_ws;                    // 128 KB each
    float* buf1   = buf0 + (size_t)B * N;
    float* maskT  = buf1 + (size_t)B * N;
    float* predsT = maskT + (size_t)B * N;

    hipMemsetAsync(maskT, 0, (size_t)B * N * sizeof(float), stream);
    prep_kernel<<<dim3((B * N) / 256), 256, 0, stream>>>(preds, seed_idx, nseeds, predsT, maskT);

    void* args[] = {(void*)&P, (void*)&predsT, (void*)&maskT,
                    (void*)&buf0, (void*)&buf1, (void*)&out};
    hipLaunchCooperativeKernel(reinterpret_cast<void*>(fused_kernel),
                               dim3(NBLK), dim3(TPB), args, 0, stream);
}

// Round 9
// 349.803 us; speedup vs baseline: 1.0087x; 1.0087x over previous
//
#include <hip/hip_runtime.h>
#include <hip/hip_cooperative_groups.h>

namespace cg = cooperative_groups;

#define B 8
#define N 4096
#define NITER 4
#define NBLK 256          // one block per CU -> cooperative co-residency guaranteed
#define TPB 1024          // 16 waves/block, 4 waves/SIMD
#define CPB (N / NBLK)    // 16 columns of the output owned per block

// Fused diffusion: P held in registers across ALL iterations (loaded once).
// Decomposition: block owns 16 output columns x all 4096 b.
//   wave w (16/block): b-range [w*256, w*256+256)
//   lane l: column c = c0 + (l&15), q = l>>4 -> b-sub-range [w*256 + q*64, +64)
//   => each lane holds p[64] = P[b][c] slice in VGPRs (64 regs).
//
// ROUND-4 LESSON: __launch_bounds__(1024,4) only sets a MIN of 4 waves/EU; the
// allocator targeted 8 waves/EU (64 VGPRs) and spilled p[64] to scratch
// (FETCH 240MB, WRITE 110MB, 255us). amdgpu_waves_per_eu(4,4) pins min=max=4
// -> 128-VGPR budget -> p[64] stays register-resident.
__global__ __launch_bounds__(TPB)
__attribute__((amdgpu_waves_per_eu(4, 4)))
void fused_kernel(
        const float* __restrict__ P,
        const float* __restrict__ predsT,   // [N][B] transposed initial preds
        const float* __restrict__ maskT,    // [N][B] transposed seed mask
        float* __restrict__ buf0,           // [N][B] ping
        float* __restrict__ buf1,           // [N][B] pong
        float* __restrict__ out)            // [B][N] final output
{
    cg::grid_group grid = cg::this_grid();

    const int tid   = threadIdx.x;
    const int wave  = tid >> 6;          // 0..15
    const int lane  = tid & 63;
    const int cc    = lane & 15;         // col within block
    const int q     = lane >> 4;         // 0..3
    const int c0    = blockIdx.x * CPB;
    const int c     = c0 + cc;
    const int bbase = wave * 256 + q * 64;

    // ---- one-time P load into registers: p[j] = P[bbase+j][c]
    // 16 consecutive cols x 4B = 64B contiguous, 64B-aligned per row-segment:
    // full transaction utilization. 64 independent loads in flight.
    float p[64];
#pragma unroll
    for (int j = 0; j < 64; ++j)
        p[j] = P[(size_t)(bbase + j) * N + c];

    __shared__ float redbuf[16][16][B];   // [wave][col][batch] = 8 KB

    for (int it = 0; it < NITER; ++it) {
        // ping-pong: it0: predsT->buf0, it1: buf0->buf1, it2: buf1->buf0, it3: buf0->out
        const float* src = (it == 0) ? predsT : ((it == 2) ? buf1 : buf0);

        float prod[B];
#pragma unroll
        for (int i = 0; i < B; ++i) prod[i] = 1.0f;

        const float* sp = src + (size_t)bbase * B;
#pragma unroll
        for (int j = 0; j < 64; ++j) {
            const float4 lo = *reinterpret_cast<const float4*>(sp + j * B);
            const float4 hi = *reinterpret_cast<const float4*>(sp + j * B + 4);
            const float pj = p[j];
            prod[0] *= fmaf(-pj, lo.x, 1.0f);
            prod[1] *= fmaf(-pj, lo.y, 1.0f);
            prod[2] *= fmaf(-pj, lo.z, 1.0f);
            prod[3] *= fmaf(-pj, lo.w, 1.0f);
            prod[4] *= fmaf(-pj, hi.x, 1.0f);
            prod[5] *= fmaf(-pj, hi.y, 1.0f);
            prod[6] *= fmaf(-pj, hi.z, 1.0f);
            prod[7] *= fmaf(-pj, hi.w, 1.0f);
        }

        // product across the 4 q-groups (lanes l, l^16, l^32, l^48 share a column)
#pragma unroll
        for (int i = 0; i < B; ++i) {
            prod[i] *= __shfl_xor(prod[i], 16);
            prod[i] *= __shfl_xor(prod[i], 32);
        }
        if (lane < 16) {
#pragma unroll
            for (int i = 0; i < B; ++i) redbuf[wave][cc][i] = prod[i];
        }
        __syncthreads();

        // wave 0: product across 16 waves; 128 (col,batch) pairs, 2 per lane
        if (wave == 0) {
#pragma unroll
            for (int rep = 0; rep < 2; ++rep) {
                const int pidx = lane + rep * 64;
                const int rc = pidx >> 3;    // col 0..15
                const int ri = pidx & 7;     // batch 0..7
                float r = 1.0f;
#pragma unroll
                for (int w = 0; w < 16; ++w) r *= redbuf[w][rc][ri];
                float v = 1.0f - r;
                if (maskT[(size_t)(c0 + rc) * B + ri] != 0.0f) v = 1.0f;
                if (it < NITER - 1) {
                    float* dst = (it == 1) ? buf1 : buf0;
                    dst[(size_t)(c0 + rc) * B + ri] = v;
                } else {
                    out[(size_t)ri * N + (c0 + rc)] = v;   // final row-major
                }
            }
        }
        if (it < NITER - 1) grid.sync();   // also provides the block-level barrier
                                           // protecting redbuf reuse next iter
    }
}

// Transpose preds into predT layout + scatter seed mask (maskT pre-zeroed by memset).
__global__ void prep_kernel(const float* __restrict__ preds,
                            const int* __restrict__ seed_idx, int nseeds,
                            float* __restrict__ predsT, float* __restrict__ maskT) {
    const int t = blockIdx.x * blockDim.x + threadIdx.x;   // t = i*N + n
    if (t < B * N) {
        const int i = t / N;
        const int n = t % N;
        predsT[(size_t)n * B + i] = preds[t];              // read coalesced, write scattered (tiny)
    }
    if (t < nseeds) {
        const int b = seed_idx[2 * t + 0];
        const int n = seed_idx[2 * t + 1];
        maskT[(size_t)n * B + b] = 1.0f;
    }
}

extern "C" void kernel_launch(void* const* d_in, const int* in_sizes, int n_in,
                              void* d_out, int out_size, void* d_ws, size_t ws_size,
                              hipStream_t stream) {
    const float* preds    = (const float*)d_in[0];   // [B, N]
    const float* P        = (const float*)d_in[1];   // [N, N]
    const int*   seed_idx = (const int*)d_in[2];     // [NSEEDS, 2]
    const int nseeds = in_sizes[2] / 2;

    float* out = (float*)d_out;                      // [B, N]
    float* buf0   = (float*)d_ws;                    // 128 KB each
    float* buf1   = buf0 + (size_t)B * N;
    float* maskT  = buf1 + (size_t)B * N;
    float* predsT = maskT + (size_t)B * N;

    hipMemsetAsync(maskT, 0, (size_t)B * N * sizeof(float), stream);
    prep_kernel<<<dim3((B * N) / 256), 256, 0, stream>>>(preds, seed_idx, nseeds, predsT, maskT);

    void* args[] = {(void*)&P, (void*)&predsT, (void*)&maskT,
                    (void*)&buf0, (void*)&buf1, (void*)&out};
    hipLaunchCooperativeKernel(reinterpret_cast<void*>(fused_kernel),
                               dim3(NBLK), dim3(TPB), args, 0, stream);
}

// Round 11
// 169.451 us; speedup vs baseline: 2.0823x; 2.0643x over previous
//
#include <hip/hip_runtime.h>

#define B 8
#define N 4096
#define NITER 4
#define NBLK 256          // one block per CU
#define TPB 1024          // 16 waves/block, 4 waves/SIMD
#define CPB 16            // columns owned per block

// One diffusion iteration. Block owns CPB=16 output columns x all 4096 b
// (same decomposition as the round-4 fused kernel, which verified absmax=0):
//   wave w: b-range [w*256, +256); lane l: col c0+(l&15), q=l>>4 -> 64 b each.
// P is STREAMED (not register-pinned): rounds 4+9 proved the allocator spills
// a p[64] array regardless of waves_per_eu pinning (VGPR stuck at 64, 94MB
// scratch WRITE). P is 64MB < 256MB L3, so iters 2-4 re-read it from Infinity
// Cache; register residency was only worth ~15us and cost 180us of scratch.
// Global sync between iterations = kernel boundary (graph-captured, cheap).
//
// XCD-pair swizzle: a 16-col block reads 64B half-lines of P; hw maps
// bid -> XCD bid%8 round-robin, so colgroup=(bid&7)*32+(bid>>3) gives each XCD
// 32 contiguous colgroups -> both 64B halves of every 128B line are consumed
// by blocks on the SAME XCD's L2 -> each line fetched from HBM once.
__global__ __launch_bounds__(TPB) void step_kernel(
        const float* __restrict__ P,
        const float* __restrict__ srcT,   // [N][B] current pred, transposed
        const float* __restrict__ maskT,  // [N][B] seed mask, transposed
        float* __restrict__ dstT,         // [N][B] next pred (if !last)
        float* __restrict__ out,          // [B][N] final output (if last)
        int last)
{
    const int tid   = threadIdx.x;
    const int wave  = tid >> 6;          // 0..15
    const int lane  = tid & 63;
    const int cc    = lane & 15;         // col within block
    const int q     = lane >> 4;         // 0..3
    const int colgroup = (blockIdx.x & 7) * 32 + (blockIdx.x >> 3);  // bijective 8x32 transpose
    const int c0    = colgroup * CPB;
    const int c     = c0 + cc;
    const int bbase = wave * 256 + q * 64;

    float prod[B];
#pragma unroll
    for (int i = 0; i < B; ++i) prod[i] = 1.0f;

    const float* Pp = P + (size_t)bbase * N + c;
    const float* sp = srcT + (size_t)bbase * B;

    // unroll 4: 4 P-loads (HBM/L3) + 8 pred-loads (L2-hot, 16-lane-shared) in
    // flight per wave; x16 waves/CU = 16KB+ P bytes in flight > ~9KB needed
    // to cover HBM latency. Register window ~56 VGPR -> no spill at any
    // occupancy target.
#pragma unroll 4
    for (int j = 0; j < 64; ++j) {
        const float pj = Pp[(size_t)j * N];                              // coalesced 64B/16 lanes
        const float4 lo = *reinterpret_cast<const float4*>(sp + j * B);  // broadcast across 16 lanes
        const float4 hi = *reinterpret_cast<const float4*>(sp + j * B + 4);
        prod[0] *= fmaf(-pj, lo.x, 1.0f);
        prod[1] *= fmaf(-pj, lo.y, 1.0f);
        prod[2] *= fmaf(-pj, lo.z, 1.0f);
        prod[3] *= fmaf(-pj, lo.w, 1.0f);
        prod[4] *= fmaf(-pj, hi.x, 1.0f);
        prod[5] *= fmaf(-pj, hi.y, 1.0f);
        prod[6] *= fmaf(-pj, hi.z, 1.0f);
        prod[7] *= fmaf(-pj, hi.w, 1.0f);
    }

    // product across the 4 q-groups (lanes l, l^16, l^32, l^48 share a column)
#pragma unroll
    for (int i = 0; i < B; ++i) {
        prod[i] *= __shfl_xor(prod[i], 16);
        prod[i] *= __shfl_xor(prod[i], 32);
    }

    __shared__ float redbuf[16][16][B];   // [wave][col][batch] = 8 KB
    if (lane < 16) {
#pragma unroll
        for (int i = 0; i < B; ++i) redbuf[wave][cc][i] = prod[i];
    }
    __syncthreads();

    // wave 0: product across 16 waves; 128 (col,batch) pairs, 2 per lane
    if (wave == 0) {
#pragma unroll
        for (int rep = 0; rep < 2; ++rep) {
            const int pidx = lane + rep * 64;
            const int rc = pidx >> 3;    // col 0..15
            const int ri = pidx & 7;     // batch 0..7
            float r = 1.0f;
#pragma unroll
            for (int w = 0; w < 16; ++w) r *= redbuf[w][rc][ri];
            float v = 1.0f - r;
            if (maskT[(size_t)(c0 + rc) * B + ri] != 0.0f) v = 1.0f;
            if (!last) dstT[(size_t)(c0 + rc) * B + ri] = v;
            else       out[(size_t)ri * N + (c0 + rc)] = v;   // final row-major
        }
    }
}

// Transpose preds into predT layout + scatter seed mask (maskT pre-zeroed by memset).
__global__ void prep_kernel(const float* __restrict__ preds,
                            const int* __restrict__ seed_idx, int nseeds,
                            float* __restrict__ predsT, float* __restrict__ maskT) {
    const int t = blockIdx.x * blockDim.x + threadIdx.x;   // t = i*N + n
    if (t < B * N) {
        const int i = t / N;
        const int n = t % N;
        predsT[(size_t)n * B + i] = preds[t];              // read coalesced, write scattered (tiny)
    }
    if (t < nseeds) {
        const int b = seed_idx[2 * t + 0];
        const int n = seed_idx[2 * t + 1];
        maskT[(size_t)n * B + b] = 1.0f;
    }
}

extern "C" void kernel_launch(void* const* d_in, const int* in_sizes, int n_in,
                              void* d_out, int out_size, void* d_ws, size_t ws_size,
                              hipStream_t stream) {
    const float* preds    = (const float*)d_in[0];   // [B, N]
    const float* P        = (const float*)d_in[1];   // [N, N]
    const int*   seed_idx = (const int*)d_in[2];     // [NSEEDS, 2]
    const int nseeds = in_sizes[2] / 2;

    float* out  = (float*)d_out;                     // [B, N]
    float* bufA  = (float*)d_ws;                     // 128 KB each
    float* bufB  = bufA + (size_t)B * N;
    float* maskT = bufB + (size_t)B * N;

    hipMemsetAsync(maskT, 0, (size_t)B * N * sizeof(float), stream);
    prep_kernel<<<dim3((B * N) / 256), 256, 0, stream>>>(preds, seed_idx, nseeds, bufA, maskT);

    // it0: A->B, it1: B->A, it2: A->B, it3: B->out
    float* src = bufA;
    float* dst = bufB;
    for (int it = 0; it < NITER; ++it) {
        const int last = (it == NITER - 1);
        step_kernel<<<dim3(NBLK), dim3(TPB), 0, stream>>>(P, src, maskT, dst, out, last);
        float* tmp = src; src = dst; dst = tmp;
    }
}

// Round 12
// 162.519 us; speedup vs baseline: 2.1711x; 1.0427x over previous
//
#include <hip/hip_runtime.h>

#define B 8
#define N 4096
#define NITER 4
#define TPB 1024
#define NBLK 256
#define COLS 32            // cols per block: 32 x 4B = exactly one 128B L2 line per P row
#define NCG (N / COLS)     // 128 colgroups
#define NBS 2              // b-slices (NBLK / NCG)
#define BSLEN (N / NBS)    // 2048 rows per slice

// One diffusion iteration, partial over a b-slice.
// Block = (colgroup, bslice): owns 32 output cols x 2048 b.
//   wave w (16): b-range [bslice*2048 + w*128, +128)
//   lane l: cc2 = l&15 -> cols c0+2*cc2, c0+2*cc2+1 (float2 of P)
//           q = l>>4  -> 32 b each
// KEY CHANGE vs r11 (40us/step, ~3x over roofline): each q-group request is
// now a FULL 128B line owned exclusively by this block (r11's 16-col blocks
// issued 64B half-lines whose pair half lived in another block; 8MB/XCD
// working set > 4MB L2 -> every line transported twice). Here no line is
// shared between blocks -> P moves HBM/L3->L2 exactly once.
// Register budget: 16 prod + ~40-float load window + addr ~= 60 VGPR, inside
// the 64-VGPR envelope the allocator enforces at TPB=1024 (round-9 lesson).
__global__ __launch_bounds__(TPB) void step_kernel(
        const float* __restrict__ P,
        const float* __restrict__ srcT,   // [N][B] current pred, transposed
        float* __restrict__ partial)      // [NBS][N][B] partial products
{
    const int tid  = threadIdx.x;
    const int wave = tid >> 6;
    const int lane = tid & 63;
    const int cc2  = lane & 15;
    const int q    = lane >> 4;
    const int colgroup = blockIdx.x & (NCG - 1);
    const int bslice   = blockIdx.x >> 7;          // NCG = 128
    const int c0    = colgroup * COLS;
    const int qbase = bslice * BSLEN + wave * (BSLEN / 16) + q * (BSLEN / 64);

    float pr0[B], pr1[B];
#pragma unroll
    for (int i = 0; i < B; ++i) { pr0[i] = 1.0f; pr1[i] = 1.0f; }

    const float* Pp = P + (size_t)qbase * N + c0 + cc2 * 2;
    const float* sp = srcT + (size_t)qbase * B;

#pragma unroll 4
    for (int j = 0; j < BSLEN / 64; ++j) {         // 32 iterations
        const float2 p2 = *reinterpret_cast<const float2*>(Pp + (size_t)j * N);
        const float4 lo = *reinterpret_cast<const float4*>(sp + j * B);      // 16-lane broadcast, L1/L2-hot
        const float4 hi = *reinterpret_cast<const float4*>(sp + j * B + 4);
        pr0[0] *= fmaf(-p2.x, lo.x, 1.0f);  pr1[0] *= fmaf(-p2.y, lo.x, 1.0f);
        pr0[1] *= fmaf(-p2.x, lo.y, 1.0f);  pr1[1] *= fmaf(-p2.y, lo.y, 1.0f);
        pr0[2] *= fmaf(-p2.x, lo.z, 1.0f);  pr1[2] *= fmaf(-p2.y, lo.z, 1.0f);
        pr0[3] *= fmaf(-p2.x, lo.w, 1.0f);  pr1[3] *= fmaf(-p2.y, lo.w, 1.0f);
        pr0[4] *= fmaf(-p2.x, hi.x, 1.0f);  pr1[4] *= fmaf(-p2.y, hi.x, 1.0f);
        pr0[5] *= fmaf(-p2.x, hi.y, 1.0f);  pr1[5] *= fmaf(-p2.y, hi.y, 1.0f);
        pr0[6] *= fmaf(-p2.x, hi.z, 1.0f);  pr1[6] *= fmaf(-p2.y, hi.z, 1.0f);
        pr0[7] *= fmaf(-p2.x, hi.w, 1.0f);  pr1[7] *= fmaf(-p2.y, hi.w, 1.0f);
    }

    // product across the 4 q-groups (lanes l, l^16, l^32, l^48 share cols)
#pragma unroll
    for (int i = 0; i < B; ++i) {
        pr0[i] *= __shfl_xor(pr0[i], 16);  pr0[i] *= __shfl_xor(pr0[i], 32);
        pr1[i] *= __shfl_xor(pr1[i], 16);  pr1[i] *= __shfl_xor(pr1[i], 32);
    }

    __shared__ float red[16][16][2][B];   // [wave][cc2][col-half][batch] = 16 KB
    if (lane < 16) {
#pragma unroll
        for (int i = 0; i < B; ++i) {
            red[wave][cc2][0][i] = pr0[i];
            red[wave][cc2][1][i] = pr1[i];
        }
    }
    __syncthreads();

    // 256 threads: product across 16 waves, write partial coalesced.
    // lane t reads word t of red[w] -> banks 2-way across the 64 lanes (free).
    if (tid < COLS * B) {
        const int col = tid >> 3;          // 0..31
        const int ri  = tid & 7;           // batch
        float r = 1.0f;
#pragma unroll
        for (int w = 0; w < 16; ++w) r *= red[w][col >> 1][col & 1][ri];
        partial[(size_t)bslice * (N * B) + (size_t)c0 * B + tid] = r;
    }
}

// out/dstT[a,i] = seed ? 1 : 1 - partial[0][a][i]*partial[1][a][i]
__global__ __launch_bounds__(256) void combine_kernel(
        const float* __restrict__ partial,
        const float* __restrict__ maskT,
        float* __restrict__ dstT,         // [N][B] next pred (if !last)
        float* __restrict__ out,          // [B][N] final (if last)
        int last)
{
    const int t = blockIdx.x * 256 + threadIdx.x;   // t = a*B + i
    const float r = partial[t] * partial[(size_t)N * B + t];
    float v = 1.0f - r;
    if (maskT[t] != 0.0f) v = 1.0f;
    if (!last) dstT[t] = v;                          // coalesced
    else out[(size_t)(t & 7) * N + (t >> 3)] = v;    // final row-major scatter (128KB, cheap)
}

// Transpose preds into [N][B] + scatter seed mask (maskT pre-zeroed by memset).
__global__ void prep_kernel(const float* __restrict__ preds,
                            const int* __restrict__ seed_idx, int nseeds,
                            float* __restrict__ predsT, float* __restrict__ maskT) {
    const int t = blockIdx.x * blockDim.x + threadIdx.x;   // t = i*N + n
    if (t < B * N) {
        const int i = t / N;
        const int n = t % N;
        predsT[(size_t)n * B + i] = preds[t];
    }
    if (t < nseeds) {
        const int b = seed_idx[2 * t + 0];
        const int n = seed_idx[2 * t + 1];
        maskT[(size_t)n * B + b] = 1.0f;
    }
}

extern "C" void kernel_launch(void* const* d_in, const int* in_sizes, int n_in,
                              void* d_out, int out_size, void* d_ws, size_t ws_size,
                              hipStream_t stream) {
    const float* preds    = (const float*)d_in[0];   // [B, N]
    const float* P        = (const float*)d_in[1];   // [N, N]
    const int*   seed_idx = (const int*)d_in[2];     // [NSEEDS, 2]
    const int nseeds = in_sizes[2] / 2;

    float* out     = (float*)d_out;                  // [B, N]
    float* bufA    = (float*)d_ws;                   // 128 KB each
    float* bufB    = bufA + (size_t)B * N;
    float* maskT   = bufB + (size_t)B * N;
    float* partial = maskT + (size_t)B * N;          // NBS*B*N = 256 KB

    hipMemsetAsync(maskT, 0, (size_t)B * N * sizeof(float), stream);
    prep_kernel<<<dim3((B * N) / 256), 256, 0, stream>>>(preds, seed_idx, nseeds, bufA, maskT);

    float* src = bufA;
    float* dst = bufB;
    for (int it = 0; it < NITER; ++it) {
        const int last = (it == NITER - 1);
        step_kernel<<<dim3(NBLK), dim3(TPB), 0, stream>>>(P, src, partial);
        combine_kernel<<<dim3((B * N) / 256), 256, 0, stream>>>(partial, maskT, dst, out, last);
        float* tmp = src; src = dst; dst = tmp;
    }
}